// Round 2
// baseline (17699.527 us; speedup 1.0000x reference)
//
#include <hip/hip_runtime.h>
#include <cstdint>
#include <cstddef>

#define NREL 8
#define NG 64
#define LN_EPS 1e-5f
#define NEG_SLOPE 0.01f

// ------------------------------------------------------------------
// setup kernels
// ------------------------------------------------------------------
__global__ void count_edges_k(const int* __restrict__ dst, const int* __restrict__ et,
                              int* __restrict__ cnt, int E) {
  int e = blockIdx.x * blockDim.x + threadIdx.x;
  if (e < E) atomicAdd(&cnt[dst[e] * NREL + et[e]], 1);
}

__global__ void make_inv_k(const int* __restrict__ cnt, float* __restrict__ inv, int n) {
  int i = blockIdx.x * blockDim.x + threadIdx.x;
  if (i < n) inv[i] = 1.0f / fmaxf((float)cnt[i], 1.0f);
}

// batch sorted: per-graph node count via binary search
__global__ void graph_inv_k(const int* __restrict__ batch, float* __restrict__ ginv, int N) {
  int g = threadIdx.x;
  if (g >= NG) return;
  int a, b;
  { int l = 0, h = N; while (l < h) { int m = (l + h) >> 1; if (batch[m] < g) l = m + 1; else h = m; } a = l; }
  { int l = 0, h = N; while (l < h) { int m = (l + h) >> 1; if (batch[m] < g + 1) l = m + 1; else h = m; } b = l; }
  ginv[g] = 1.0f / fmaxf((float)(b - a), 1.0f);
}

// ------------------------------------------------------------------
// edge aggregation (C=128 always): S[dst, r-r0, :] += invcnt(dst,r) * x[src, :]
// thread per (edge, float4 chunk); 32 consecutive threads share one edge
// ------------------------------------------------------------------
__global__ void agg_k(const int* __restrict__ src, const int* __restrict__ dst,
                      const int* __restrict__ et, const float* __restrict__ xin,
                      const float* __restrict__ invcnt, float* __restrict__ S,
                      int E, int r0, int rc) {
  int gid = blockIdx.x * blockDim.x + threadIdx.x;
  int e = gid >> 5;
  int c4 = gid & 31;
  if (e >= E) return;
  int r = et[e];
  if (r < r0 || r >= r0 + rc) return;
  int d = dst[e];
  float inv = invcnt[d * NREL + r];
  int s = src[e];
  float4 v = *(const float4*)(xin + (size_t)s * 128 + c4 * 4);
  float* o = S + (size_t)d * ((size_t)rc * 128) + (size_t)(r - r0) * 128 + c4 * 4;
  atomicAdd(o + 0, v.x * inv);
  atomicAdd(o + 1, v.y * inv);
  atomicAdd(o + 2, v.z * inv);
  atomicAdd(o + 3, v.w * inv);
}

// ------------------------------------------------------------------
// f32 GEMM: C[m,n] (+)= sum_k A[m,k]*B[k,n]; A row stride = lda.
// BT: B stored (N,K) row-major. BM=BN=64, BK=16, 256 thr, 4x4/thread.
// ------------------------------------------------------------------
template<bool BT, bool ACC, bool ACT>
__global__ __launch_bounds__(256)
void gemm_f32(const float* __restrict__ A, const float* __restrict__ B,
              const float* __restrict__ bias, float* __restrict__ C,
              int M, int N, int K, int lda) {
  __shared__ float As[16][65];
  __shared__ float Bs[16][64];
  int bm = blockIdx.x * 64;
  int bn = blockIdx.y * 64;
  int t = threadIdx.x;
  int tn = t & 15, tm = t >> 4;
  float acc[4][4] = {};
  for (int k0 = 0; k0 < K; k0 += 16) {
    {
      int lin = t * 4;
      int m = lin >> 4;       // t/4
      int k = lin & 15;       // 4*(t%4)
      int gm = bm + m;
      float4 v = make_float4(0.f, 0.f, 0.f, 0.f);
      if (gm < M) v = *(const float4*)(A + (size_t)gm * lda + k0 + k);
      As[k + 0][m] = v.x; As[k + 1][m] = v.y; As[k + 2][m] = v.z; As[k + 3][m] = v.w;
    }
    if (!BT) {
      int lin = t * 4;
      int k = lin >> 6;       // t/16
      int n = lin & 63;       // 4*(t%16)
      float4 v = *(const float4*)(B + (size_t)(k0 + k) * N + bn + n);
      *(float4*)&Bs[k][n] = v;
    } else {
      int lin = t * 4;
      int n = lin >> 4;
      int k = lin & 15;
      float4 v = *(const float4*)(B + (size_t)(bn + n) * K + k0 + k);
      Bs[k + 0][n] = v.x; Bs[k + 1][n] = v.y; Bs[k + 2][n] = v.z; Bs[k + 3][n] = v.w;
    }
    __syncthreads();
#pragma unroll
    for (int kk = 0; kk < 16; ++kk) {
      float a[4], b[4];
#pragma unroll
      for (int i = 0; i < 4; ++i) a[i] = As[kk][tm * 4 + i];
#pragma unroll
      for (int j = 0; j < 4; ++j) b[j] = Bs[kk][tn * 4 + j];
#pragma unroll
      for (int i = 0; i < 4; ++i)
#pragma unroll
        for (int j = 0; j < 4; ++j)
          acc[i][j] = fmaf(a[i], b[j], acc[i][j]);
    }
    __syncthreads();
  }
#pragma unroll
  for (int i = 0; i < 4; ++i) {
    int gm = bm + tm * 4 + i;
    if (gm >= M) continue;
#pragma unroll
    for (int j = 0; j < 4; ++j) {
      int gn = bn + tn * 4 + j;
      float v = acc[i][j];
      if (ACC) v += C[(size_t)gm * N + gn];
      else     v += bias[gn];
      if (ACT) v = v > 0.f ? v : NEG_SLOPE * v;
      C[(size_t)gm * N + gn] = v;
    }
  }
}

// ------------------------------------------------------------------
// per-graph sum (batch sorted): block = npb consecutive nodes, C threads
// ------------------------------------------------------------------
__global__ void gap_sum_k(const float* __restrict__ x, const int* __restrict__ batch,
                          float* __restrict__ out, int N, int C, int npb) {
  int d = threadIdx.x;            // blockDim.x == C
  int n0 = blockIdx.x * npb;
  if (n0 >= N) return;
  int n1 = min(n0 + npb, N);
  float acc = 0.f;
  int g = batch[n0];
  for (int n = n0; n < n1; ++n) {
    int gn = batch[n];
    if (gn != g) { atomicAdd(&out[g * C + d], acc); acc = 0.f; g = gn; }
    acc += x[(size_t)n * C + d];
  }
  atomicAdd(&out[g * C + d], acc);
}

// x[n,:] += gap[batch[n],:] * ginv[batch[n]]   (in-place se)
__global__ void se_k(float* __restrict__ x, const float* __restrict__ gap,
                     const float* __restrict__ ginv, const int* __restrict__ batch, int N) {
  int gid = blockIdx.x * blockDim.x + threadIdx.x;
  int n = gid >> 5;
  int c4 = gid & 31;
  if (n >= N) return;
  int g = batch[n];
  float gi = ginv[g];
  float4 v = *(float4*)(x + (size_t)n * 128 + c4 * 4);
  float4 s = *(const float4*)(gap + (size_t)g * 128 + c4 * 4);
  v.x += s.x * gi; v.y += s.y * gi; v.z += s.z * gi; v.w += s.w * gi;
  *(float4*)(x + (size_t)n * 128 + c4 * 4) = v;
}

// out = LN(a + b)*g + be, rows of 256; one wave per row, 4 rows/block
__global__ void ln_add_k(const float* __restrict__ a, const float* __restrict__ b,
                         const float* __restrict__ g, const float* __restrict__ be,
                         float* __restrict__ out, int N) {
  int wid = threadIdx.x >> 6, lane = threadIdx.x & 63;
  int n = blockIdx.x * 4 + wid;
  if (n >= N) return;
  float4 va = *(const float4*)(a + (size_t)n * 256 + lane * 4);
  float4 vb = *(const float4*)(b + (size_t)n * 256 + lane * 4);
  float x0 = va.x + vb.x, x1 = va.y + vb.y, x2 = va.z + vb.z, x3 = va.w + vb.w;
  float s = x0 + x1 + x2 + x3;
#pragma unroll
  for (int o = 32; o > 0; o >>= 1) s += __shfl_xor(s, o);
  float m = s * (1.0f / 256.0f);
  float d0 = x0 - m, d1 = x1 - m, d2 = x2 - m, d3 = x3 - m;
  float ss = d0 * d0 + d1 * d1 + d2 * d2 + d3 * d3;
#pragma unroll
  for (int o = 32; o > 0; o >>= 1) ss += __shfl_xor(ss, o);
  float rinv = rsqrtf(ss * (1.0f / 256.0f) + LN_EPS);
  float4 vg = *(const float4*)(g + lane * 4);
  float4 vbe = *(const float4*)(be + lane * 4);
  float4 ov;
  ov.x = d0 * rinv * vg.x + vbe.x;
  ov.y = d1 * rinv * vg.y + vbe.y;
  ov.z = d2 * rinv * vg.z + vbe.z;
  ov.w = d3 * rinv * vg.w + vbe.w;
  *(float4*)(out + (size_t)n * 256 + lane * 4) = ov;
}

// out[g,cls] = (psum[g]*ginv[g]).out_w[cls] + out_b[cls]
__global__ void head_k(const float* __restrict__ psum, const float* __restrict__ ginv,
                       const float* __restrict__ ow, const float* __restrict__ ob,
                       float* __restrict__ out) {
  int gr = blockIdx.x;
  int lane = threadIdx.x;
  float gi = ginv[gr];
  float4 v = *(const float4*)(psum + gr * 256 + lane * 4);
  float p0 = v.x * gi, p1 = v.y * gi, p2 = v.z * gi, p3 = v.w * gi;
  for (int cls = 0; cls < 10; ++cls) {
    float4 w = *(const float4*)(ow + cls * 256 + lane * 4);
    float s = p0 * w.x + p1 * w.y + p2 * w.z + p3 * w.w;
#pragma unroll
    for (int o = 32; o > 0; o >>= 1) s += __shfl_xor(s, o);
    if (lane == 0) out[gr * 10 + cls] = s + ob[cls];
  }
}

// ------------------------------------------------------------------
extern "C" void kernel_launch(void* const* d_in, const int* in_sizes, int n_in,
                              void* d_out, int out_size, void* d_ws, size_t ws_size,
                              hipStream_t stream) {
  const float* x        = (const float*)d_in[0];
  const int*   eidx     = (const int*)d_in[1];
  const int*   eattr    = (const int*)d_in[2];
  const int*   batch    = (const int*)d_in[3];
  const float* Ws       = (const float*)d_in[4];
  const float* Rs       = (const float*)d_in[5];
  const float* Bsb      = (const float*)d_in[6];
  const float* Wf1      = (const float*)d_in[7];
  const float* Rf1      = (const float*)d_in[8];
  const float* Bf1      = (const float*)d_in[9];
  const float* Wf23     = (const float*)d_in[10];
  const float* Rf23     = (const float*)d_in[11];
  const float* Bf23     = (const float*)d_in[12];
  const float* Wf4      = (const float*)d_in[13];
  const float* Rf4      = (const float*)d_in[14];
  const float* Bf4      = (const float*)d_in[15];
  const float* attn_in_w  = (const float*)d_in[16];
  const float* attn_in_b  = (const float*)d_in[17];
  const float* attn_out_w = (const float*)d_in[18];
  const float* attn_out_b = (const float*)d_in[19];
  const float* enc_fc_w   = (const float*)d_in[20];
  const float* enc_fc_b   = (const float*)d_in[21];
  const float* ln_g       = (const float*)d_in[22];
  const float* ln_b       = (const float*)d_in[23];
  const float* out_w      = (const float*)d_in[24];
  const float* out_b      = (const float*)d_in[25];

  const int N = in_sizes[0] / 128;
  const int E = in_sizes[1] / 2;
  const int* src = eidx;
  const int* dst = eidx + E;
  const size_t NB = (size_t)N * 128 * 4;   // one N x 128 f32 region (multiple of 256B)

  // ---- workspace layout (fixed ~157 MB + adaptive S) ----
  // ginv/psum/gap live at the base (needed after the MLP overlay phase).
  // t2 overlays R4 + (cnt,invc,S-head) — all dead by the MLP phase.
  char* p = (char*)d_ws;
  auto alloc = [&](size_t bytes) {
    char* r = p;
    p += (bytes + 255) & ~(size_t)255;
    return r;
  };
  float* ginv = (float*)alloc(NG * 4);
  float* psum = (float*)alloc(NG * 256 * 4);
  float* gapb = (float*)alloc(NG * 128 * 4);
  float* R0 = (float*)alloc(NB);   // x1
  float* R1 = (float*)alloc(NB);   // x2
  float* R2 = (float*)alloc(NB);   // x3
  float* R3 = (float*)alloc(NB);   // hbuf
  float* R4 = (float*)alloc(NB);   // hb2
  int*   cnt  = (int*)  alloc((size_t)N * NREL * 4);
  float* invc = (float*)alloc((size_t)N * NREL * 4);
  size_t used = (size_t)(p - (char*)d_ws);
  float* S = (float*)p;
  size_t s_bytes = ws_size > used ? ws_size - used : 0;

  float* x1 = R0, *x2 = R1, *x3 = R2, *hbuf = R3, *hb2 = R4;
  float* qbuf = R0;   // N x 256, spans R0+R1
  float* t1   = R2;   // N x 256, spans R2+R3
  float* t2   = R4;   // N x 256, spans R4 + cnt/invc/S-head (dead by then)

  int rcmax = (int)(s_bytes / NB);
  if (rcmax > NREL) rcmax = NREL;
  if (rcmax < 1) rcmax = 1;

  auto cdiv = [](long long a, long long b) { return (int)((a + b - 1) / b); };

  // ---- edge-structure precompute (shared by all 7 RGCN layers) ----
  hipMemsetAsync(cnt, 0, (size_t)N * NREL * 4, stream);
  count_edges_k<<<cdiv(E, 256), 256, 0, stream>>>(dst, eattr, cnt, E);
  make_inv_k<<<cdiv((long long)N * NREL, 256), 256, 0, stream>>>(cnt, invc, N * NREL);
  graph_inv_k<<<1, 64, 0, stream>>>(batch, ginv, N);

  // message pass: out += sum_r agg_r(xsrc) @ W_r  (each W_r block = 128 rows x D
  // at Wb + r*wstride); fin: apply leaky-relu on the very last accumulation
  auto msg_pass = [&](const float* xsrc, const float* Wb, size_t wstride, int D,
                      float* out, bool fin) {
    dim3 grid(cdiv(N, 64), D / 64);
    for (int r0 = 0; r0 < NREL; r0 += rcmax) {
      int rc = (NREL - r0 < rcmax) ? (NREL - r0) : rcmax;
      hipMemsetAsync(S, 0, (size_t)N * rc * 128 * 4, stream);
      agg_k<<<cdiv((long long)E * 32, 256), 256, 0, stream>>>(src, dst, eattr, xsrc, invc, S, E, r0, rc);
      for (int r = 0; r < rc; ++r) {
        bool last = fin && (r0 + r == NREL - 1);
        const float* Bp = Wb + (size_t)(r0 + r) * wstride;
        if (last)
          gemm_f32<false, true, true><<<grid, 256, 0, stream>>>(S + r * 128, Bp, nullptr, out, N, D, 128, rc * 128);
        else
          gemm_f32<false, true, false><<<grid, 256, 0, stream>>>(S + r * 128, Bp, nullptr, out, N, D, 128, rc * 128);
      }
    }
  };

  // RGCN layer, 128-wide input
  auto layer128 = [&](const float* xin, const float* W, const float* root,
                      const float* bias, float* out) {
    dim3 grid(cdiv(N, 64), 2);
    gemm_f32<false, false, false><<<grid, 256, 0, stream>>>(xin, root, bias, out, N, 128, 128, 128);
    msg_pass(xin, W, (size_t)128 * 128, 128, out, true);
  };

  // RGCN layer on conceptual cat [h | se] without materializing it
  auto layer256 = [&](const float* h, const float* se, const float* W /*(8,256,D)*/,
                      const float* root /*(256,D)*/, const float* bias, float* out, int D) {
    dim3 grid(cdiv(N, 64), D / 64);
    gemm_f32<false, false, false><<<grid, 256, 0, stream>>>(h, root, bias, out, N, D, 128, 128);
    gemm_f32<false, true, false><<<grid, 256, 0, stream>>>(se, root + (size_t)128 * D, nullptr, out, N, D, 128, 128);
    msg_pass(h,  W,                    (size_t)256 * D, D, out, false);
    msg_pass(se, W + (size_t)128 * D,  (size_t)256 * D, D, out, true);
  };

  auto apply_se = [&](float* xk) {   // xk += gap(xk)[batch] (in place)
    hipMemsetAsync(gapb, 0, NG * 128 * 4, stream);
    gap_sum_k<<<cdiv(N, 64), 128, 0, stream>>>(xk, batch, gapb, N, 128, 64);
    se_k<<<cdiv((long long)N * 32, 256), 256, 0, stream>>>(xk, gapb, ginv, batch, N);
  };

  // ---- the 7 RGCN layers ----
  layer128(x,  Ws,                       Rs,                  Bsb,       x1);
  layer128(x1, Ws + 1 * 8 * 128 * 128,   Rs + 1 * 128 * 128,  Bsb + 128, x2);
  layer128(x2, Ws + 2 * 8 * 128 * 128,   Rs + 2 * 128 * 128,  Bsb + 256, x3);
  layer128(x,  Wf1,                      Rf1,                 Bf1,       hbuf);

  apply_se(x1);   // x1 := se1
  layer256(hbuf, x1, Wf23,                     Rf23,              Bf23,       hb2,  128);
  apply_se(x2);   // x2 := se2
  layer256(hb2,  x2, Wf23 + 8 * 256 * 128,     Rf23 + 256 * 128,  Bf23 + 128, hbuf, 128);
  apply_se(x3);   // x3 := se3
  layer256(hbuf, x3, Wf4,                      Rf4,               Bf4,        qbuf, 256);

  // ---- degenerate MHA (softmax over size-1 axis == 1 => o == v) + encoder ----
  dim3 g256(cdiv(N, 64), 4);
  gemm_f32<true, false, false><<<g256, 256, 0, stream>>>(qbuf, attn_in_w + (size_t)512 * 256,
                                                         attn_in_b + 512, t1, N, 256, 256, 256);
  gemm_f32<true, false, false><<<g256, 256, 0, stream>>>(t1, attn_out_w, attn_out_b, t2, N, 256, 256, 256);
  ln_add_k<<<cdiv(N, 4), 256, 0, stream>>>(t2, qbuf, ln_g, ln_b, t1, N);     // a
  gemm_f32<true, false, false><<<g256, 256, 0, stream>>>(t1, enc_fc_w, enc_fc_b, t2, N, 256, 256, 256);
  ln_add_k<<<cdiv(N, 4), 256, 0, stream>>>(t2, t1, ln_g, ln_b, qbuf, N);     // o

  // pooled + classifier head
  hipMemsetAsync(psum, 0, NG * 256 * 4, stream);
  gap_sum_k<<<cdiv(N, 64), 256, 0, stream>>>(qbuf, batch, psum, N, 256, 64);
  head_k<<<64, 64, 0, stream>>>(psum, ginv, out_w, out_b, (float*)d_out);
}

// Round 3
// 4354.004 us; speedup vs baseline: 4.0651x; 4.0651x over previous
//
#include <hip/hip_runtime.h>
#include <cstdint>
#include <cstddef>

#define NREL 8
#define NG 64
#define LN_EPS 1e-5f
#define NEG_SLOPE 0.01f

// ------------------------------------------------------------------
// setup kernels
// ------------------------------------------------------------------
__global__ void count_edges_k(const int* __restrict__ dst, const int* __restrict__ et,
                              int* __restrict__ cnt, int E) {
  int e = blockIdx.x * blockDim.x + threadIdx.x;
  if (e < E) atomicAdd(&cnt[dst[e] * NREL + et[e]], 1);
}

// batch sorted: per-graph node count via binary search
__global__ void graph_inv_k(const int* __restrict__ batch, float* __restrict__ ginv, int N) {
  int g = threadIdx.x;
  if (g >= NG) return;
  int a, b;
  { int l = 0, h = N; while (l < h) { int m = (l + h) >> 1; if (batch[m] < g) l = m + 1; else h = m; } a = l; }
  { int l = 0, h = N; while (l < h) { int m = (l + h) >> 1; if (batch[m] < g + 1) l = m + 1; else h = m; } b = l; }
  ginv[g] = 1.0f / fmaxf((float)(b - a), 1.0f);
}

// ---- 3-kernel exclusive scan over NK ints (NK ~ 400k) ----
#define SCAN_B 256
#define SCAN_I 4   // 1024 elems per block

__global__ void scan1_k(const int* __restrict__ in, int* __restrict__ out,
                        int* __restrict__ bsum, int n) {
  __shared__ int sh[SCAN_B];
  int b0 = blockIdx.x * (SCAN_B * SCAN_I);
  int t = threadIdx.x;
  int v[SCAN_I]; int s = 0;
#pragma unroll
  for (int i = 0; i < SCAN_I; ++i) {
    int idx = b0 + t * SCAN_I + i;
    v[i] = idx < n ? in[idx] : 0;
    s += v[i];
  }
  sh[t] = s; __syncthreads();
  for (int off = 1; off < SCAN_B; off <<= 1) {
    int x = (t >= off) ? sh[t - off] : 0; __syncthreads();
    sh[t] += x; __syncthreads();
  }
  int excl = sh[t] - s;
  if (t == SCAN_B - 1) bsum[blockIdx.x] = sh[t];
  int run = excl;
#pragma unroll
  for (int i = 0; i < SCAN_I; ++i) {
    int idx = b0 + t * SCAN_I + i;
    if (idx < n) out[idx] = run;
    run += v[i];
  }
}

__global__ void scan2_k(int* __restrict__ bsum, int nb) {  // single block of 1024
  __shared__ int sh[1024];
  int t = threadIdx.x;
  int v = t < nb ? bsum[t] : 0;
  sh[t] = v; __syncthreads();
  for (int off = 1; off < 1024; off <<= 1) {
    int x = (t >= off) ? sh[t - off] : 0; __syncthreads();
    sh[t] += x; __syncthreads();
  }
  if (t < nb) bsum[t] = sh[t] - v;   // exclusive
}

__global__ void scan3_k(int* __restrict__ out, const int* __restrict__ bsum, int n, int total) {
  int idx = blockIdx.x * blockDim.x + threadIdx.x;
  if (idx < n) out[idx] += bsum[idx / (SCAN_B * SCAN_I)];
  if (idx == 0) out[n] = total;
}

__global__ void scatter_k(const int* __restrict__ src, const int* __restrict__ dst,
                          const int* __restrict__ et, int* __restrict__ cursor,
                          int* __restrict__ srcs, int E) {
  int e = blockIdx.x * blockDim.x + threadIdx.x;
  if (e >= E) return;
  int key = dst[e] * NREL + et[e];
  int p = atomicAdd(&cursor[key], 1);
  srcs[p] = src[e];
}

// ------------------------------------------------------------------
// CSR segment aggregation: S[seg,:] = (1/max(len,1)) * sum_{e in seg} x[srcs[e],:]
// seg indexes (node, r-r0) for r in [r0, r0+rc); 32 lanes per segment (128 floats)
// ------------------------------------------------------------------
__global__ void agg_csr_k(const int* __restrict__ srcs, const int* __restrict__ off,
                          const float* __restrict__ xin, float* __restrict__ S,
                          int N, int r0, int rc) {
  int gid = blockIdx.x * blockDim.x + threadIdx.x;
  int seg = gid >> 5;
  int lane = gid & 31;
  if (seg >= N * rc) return;
  int node = seg / rc;
  int r = r0 + (seg - node * rc);
  int key = node * NREL + r;
  int a = off[key], b = off[key + 1];
  float inv = 1.0f / fmaxf((float)(b - a), 1.0f);
  float4 acc = make_float4(0.f, 0.f, 0.f, 0.f);
  for (int e = a; e < b; ++e) {
    float4 v = *(const float4*)(xin + (size_t)srcs[e] * 128 + lane * 4);
    acc.x += v.x; acc.y += v.y; acc.z += v.z; acc.w += v.w;
  }
  acc.x *= inv; acc.y *= inv; acc.z *= inv; acc.w *= inv;
  *(float4*)(S + (size_t)seg * 128 + lane * 4) = acc;
}

// ------------------------------------------------------------------
// f32 GEMM: C[m,n] (+)= sum_k A[m,k]*B[brow(k),n]
// brow(k) = (k>>7)*bstep + (k&127) + boff   (identity when bstep=128, boff=0)
// BT: B stored (N,K) row-major (brow map unused). BM=128, BN=64, BK=16,
// 256 threads, 8x4 per thread.
// ------------------------------------------------------------------
template<bool BT, bool ACC, bool ACT>
__global__ __launch_bounds__(256)
void gemm_f32(const float* __restrict__ A, const float* __restrict__ B,
              const float* __restrict__ bias, float* __restrict__ C,
              int M, int N, int K, int lda, int bstep, int boff) {
  __shared__ float As[16][132];   // 132: keeps b128 rows 16B-aligned, breaks pow2 stride
  __shared__ float Bs[16][64];
  int bm = blockIdx.x * 128;
  int bn = blockIdx.y * 64;
  int t = threadIdx.x;
  int tn = t & 15, tm = t >> 4;
  float acc[8][4] = {};
  for (int k0 = 0; k0 < K; k0 += 16) {
    { // A: 128 rows x 16 k; thread: row=t>>1, k-offset=(t&1)*8
      int row = t >> 1, kof = (t & 1) * 8;
      int gm = bm + row;
      float4 v0 = make_float4(0.f, 0.f, 0.f, 0.f), v1 = v0;
      if (gm < M) {
        const float* ap = A + (size_t)gm * lda + k0 + kof;
        v0 = *(const float4*)ap;
        v1 = *(const float4*)(ap + 4);
      }
      As[kof + 0][row] = v0.x; As[kof + 1][row] = v0.y;
      As[kof + 2][row] = v0.z; As[kof + 3][row] = v0.w;
      As[kof + 4][row] = v1.x; As[kof + 5][row] = v1.y;
      As[kof + 6][row] = v1.z; As[kof + 7][row] = v1.w;
    }
    if (!BT) {
      int kb = t >> 4, n = (t & 15) * 4;
      int kk = k0 + kb;
      int brow = (kk >> 7) * bstep + (kk & 127) + boff;
      *(float4*)&Bs[kb][n] = *(const float4*)(B + (size_t)brow * N + bn + n);
    } else {
      int n = t >> 2, kof = (t & 3) * 4;
      float4 v = *(const float4*)(B + (size_t)(bn + n) * K + k0 + kof);
      Bs[kof + 0][n] = v.x; Bs[kof + 1][n] = v.y;
      Bs[kof + 2][n] = v.z; Bs[kof + 3][n] = v.w;
    }
    __syncthreads();
#pragma unroll
    for (int kk = 0; kk < 16; ++kk) {
      float a0[8], b0[4];
#pragma unroll
      for (int i = 0; i < 8; ++i) a0[i] = As[kk][tm * 8 + i];
#pragma unroll
      for (int j = 0; j < 4; ++j) b0[j] = Bs[kk][tn * 4 + j];
#pragma unroll
      for (int i = 0; i < 8; ++i)
#pragma unroll
        for (int j = 0; j < 4; ++j)
          acc[i][j] = fmaf(a0[i], b0[j], acc[i][j]);
    }
    __syncthreads();
  }
#pragma unroll
  for (int i = 0; i < 8; ++i) {
    int gm = bm + tm * 8 + i;
    if (gm >= M) continue;
    float* cp = C + (size_t)gm * N + bn + tn * 4;
    float4 v;
    if (ACC) {
      float4 c = *(const float4*)cp;
      v.x = acc[i][0] + c.x; v.y = acc[i][1] + c.y;
      v.z = acc[i][2] + c.z; v.w = acc[i][3] + c.w;
    } else {
      const float* bp = bias + bn + tn * 4;
      v.x = acc[i][0] + bp[0]; v.y = acc[i][1] + bp[1];
      v.z = acc[i][2] + bp[2]; v.w = acc[i][3] + bp[3];
    }
    if (ACT) {
      v.x = v.x > 0.f ? v.x : NEG_SLOPE * v.x;
      v.y = v.y > 0.f ? v.y : NEG_SLOPE * v.y;
      v.z = v.z > 0.f ? v.z : NEG_SLOPE * v.z;
      v.w = v.w > 0.f ? v.w : NEG_SLOPE * v.w;
    }
    *(float4*)cp = v;
  }
}

// ------------------------------------------------------------------
// per-graph sum (batch sorted): block = npb consecutive nodes, C threads
// ------------------------------------------------------------------
__global__ void gap_sum_k(const float* __restrict__ x, const int* __restrict__ batch,
                          float* __restrict__ out, int N, int C, int npb) {
  int d = threadIdx.x;            // blockDim.x == C
  int n0 = blockIdx.x * npb;
  if (n0 >= N) return;
  int n1 = min(n0 + npb, N);
  float acc = 0.f;
  int g = batch[n0];
  for (int n = n0; n < n1; ++n) {
    int gn = batch[n];
    if (gn != g) { atomicAdd(&out[g * C + d], acc); acc = 0.f; g = gn; }
    acc += x[(size_t)n * C + d];
  }
  atomicAdd(&out[g * C + d], acc);
}

// x[n,:] += gap[batch[n],:] * ginv[batch[n]]   (in-place se)
__global__ void se_k(float* __restrict__ x, const float* __restrict__ gap,
                     const float* __restrict__ ginv, const int* __restrict__ batch, int N) {
  int gid = blockIdx.x * blockDim.x + threadIdx.x;
  int n = gid >> 5;
  int c4 = gid & 31;
  if (n >= N) return;
  int g = batch[n];
  float gi = ginv[g];
  float4 v = *(float4*)(x + (size_t)n * 128 + c4 * 4);
  float4 s = *(const float4*)(gap + (size_t)g * 128 + c4 * 4);
  v.x += s.x * gi; v.y += s.y * gi; v.z += s.z * gi; v.w += s.w * gi;
  *(float4*)(x + (size_t)n * 128 + c4 * 4) = v;
}

// out = LN(a + b)*g + be, rows of 256; one wave per row, 4 rows/block
__global__ void ln_add_k(const float* __restrict__ a, const float* __restrict__ b,
                         const float* __restrict__ g, const float* __restrict__ be,
                         float* __restrict__ out, int N) {
  int wid = threadIdx.x >> 6, lane = threadIdx.x & 63;
  int n = blockIdx.x * 4 + wid;
  if (n >= N) return;
  float4 va = *(const float4*)(a + (size_t)n * 256 + lane * 4);
  float4 vb = *(const float4*)(b + (size_t)n * 256 + lane * 4);
  float x0 = va.x + vb.x, x1 = va.y + vb.y, x2 = va.z + vb.z, x3 = va.w + vb.w;
  float s = x0 + x1 + x2 + x3;
#pragma unroll
  for (int o = 32; o > 0; o >>= 1) s += __shfl_xor(s, o);
  float m = s * (1.0f / 256.0f);
  float d0 = x0 - m, d1 = x1 - m, d2 = x2 - m, d3 = x3 - m;
  float ss = d0 * d0 + d1 * d1 + d2 * d2 + d3 * d3;
#pragma unroll
  for (int o = 32; o > 0; o >>= 1) ss += __shfl_xor(ss, o);
  float rinv = rsqrtf(ss * (1.0f / 256.0f) + LN_EPS);
  float4 vg = *(const float4*)(g + lane * 4);
  float4 vbe = *(const float4*)(be + lane * 4);
  float4 ov;
  ov.x = d0 * rinv * vg.x + vbe.x;
  ov.y = d1 * rinv * vg.y + vbe.y;
  ov.z = d2 * rinv * vg.z + vbe.z;
  ov.w = d3 * rinv * vg.w + vbe.w;
  *(float4*)(out + (size_t)n * 256 + lane * 4) = ov;
}

// out[g,cls] = (psum[g]*ginv[g]).out_w[cls] + out_b[cls]
__global__ void head_k(const float* __restrict__ psum, const float* __restrict__ ginv,
                       const float* __restrict__ ow, const float* __restrict__ ob,
                       float* __restrict__ out) {
  int gr = blockIdx.x;
  int lane = threadIdx.x;
  float gi = ginv[gr];
  float4 v = *(const float4*)(psum + gr * 256 + lane * 4);
  float p0 = v.x * gi, p1 = v.y * gi, p2 = v.z * gi, p3 = v.w * gi;
  for (int cls = 0; cls < 10; ++cls) {
    float4 w = *(const float4*)(ow + cls * 256 + lane * 4);
    float s = p0 * w.x + p1 * w.y + p2 * w.z + p3 * w.w;
#pragma unroll
    for (int o = 32; o > 0; o >>= 1) s += __shfl_xor(s, o);
    if (lane == 0) out[gr * 10 + cls] = s + ob[cls];
  }
}

// ------------------------------------------------------------------
extern "C" void kernel_launch(void* const* d_in, const int* in_sizes, int n_in,
                              void* d_out, int out_size, void* d_ws, size_t ws_size,
                              hipStream_t stream) {
  const float* x        = (const float*)d_in[0];
  const int*   eidx     = (const int*)d_in[1];
  const int*   eattr    = (const int*)d_in[2];
  const int*   batch    = (const int*)d_in[3];
  const float* Ws       = (const float*)d_in[4];
  const float* Rs       = (const float*)d_in[5];
  const float* Bsb      = (const float*)d_in[6];
  const float* Wf1      = (const float*)d_in[7];
  const float* Rf1      = (const float*)d_in[8];
  const float* Bf1      = (const float*)d_in[9];
  const float* Wf23     = (const float*)d_in[10];
  const float* Rf23     = (const float*)d_in[11];
  const float* Bf23     = (const float*)d_in[12];
  const float* Wf4      = (const float*)d_in[13];
  const float* Rf4      = (const float*)d_in[14];
  const float* Bf4      = (const float*)d_in[15];
  const float* attn_in_w  = (const float*)d_in[16];
  const float* attn_in_b  = (const float*)d_in[17];
  const float* attn_out_w = (const float*)d_in[18];
  const float* attn_out_b = (const float*)d_in[19];
  const float* enc_fc_w   = (const float*)d_in[20];
  const float* enc_fc_b   = (const float*)d_in[21];
  const float* ln_g       = (const float*)d_in[22];
  const float* ln_b       = (const float*)d_in[23];
  const float* out_w      = (const float*)d_in[24];
  const float* out_b      = (const float*)d_in[25];

  const int N = in_sizes[0] / 128;
  const int E = in_sizes[1] / 2;
  const int NK = N * NREL;
  const int* src = eidx;
  const int* dst = eidx + E;
  const size_t NB = (size_t)N * 128 * 4;   // one N x 128 f32 region

  // ---- workspace layout ----
  char* p = (char*)d_ws;
  auto alloc = [&](size_t bytes) {
    char* r = p;
    p += (bytes + 255) & ~(size_t)255;
    return r;
  };
  float* ginv = (float*)alloc(NG * 4);
  float* psum = (float*)alloc(NG * 256 * 4);
  float* gapb = (float*)alloc(NG * 128 * 4);
  float* R0 = (float*)alloc(NB);   // x1 / qbuf lo
  float* R1 = (float*)alloc(NB);   // x2 / qbuf hi
  float* R2 = (float*)alloc(NB);   // x3 / t1 lo
  float* R3 = (float*)alloc(NB);   // hbuf / t1 hi
  float* R4 = (float*)alloc(NB);   // hb2 / t2 lo
  int*   cnt    = (int*)alloc((size_t)NK * 4);
  int*   off    = (int*)alloc((size_t)(NK + 1) * 4);
  int*   cursor = (int*)alloc((size_t)NK * 4);
  int*   srcs   = (int*)alloc((size_t)E * 4);
  int*   bsum   = (int*)alloc(2048 * 4);
  size_t used = (size_t)(p - (char*)d_ws);
  float* S = (float*)p;
  size_t s_bytes = ws_size > used ? ws_size - used : 0;

  float* x1 = R0, *x2 = R1, *x3 = R2, *hbuf = R3, *hb2 = R4;
  float* qbuf = R0;   // N x 256 (R0+R1)
  float* t1   = R2;   // N x 256 (R2+R3)
  float* t2   = R4;   // N x 256 (R4 + cnt/off/cursor/srcs/S-head, dead by MLP phase)

  int rcmax = (int)(s_bytes / NB);
  if (rcmax > NREL) rcmax = NREL;
  if (rcmax < 1) rcmax = 1;

  auto cdiv = [](long long a, long long b) { return (int)((a + b - 1) / b); };

  // ---- CSR build (once; reused by all 9 aggregation passes) ----
  hipMemsetAsync(cnt, 0, (size_t)NK * 4, stream);
  count_edges_k<<<cdiv(E, 256), 256, 0, stream>>>(dst, eattr, cnt, E);
  int nb = cdiv(NK, SCAN_B * SCAN_I);
  scan1_k<<<nb, SCAN_B, 0, stream>>>(cnt, off, bsum, NK);
  scan2_k<<<1, 1024, 0, stream>>>(bsum, nb);
  scan3_k<<<cdiv(NK, 256), 256, 0, stream>>>(off, bsum, NK, E);
  hipMemcpyAsync(cursor, off, (size_t)NK * 4, hipMemcpyDeviceToDevice, stream);
  scatter_k<<<cdiv(E, 256), 256, 0, stream>>>(src, dst, eattr, cursor, srcs, E);
  graph_inv_k<<<1, 64, 0, stream>>>(batch, ginv, N);

  // message pass: out += sum_r agg_r(xsrc) @ W_r, relation-chunked K=rc*128 GEMMs
  auto msg = [&](const float* xsrc, const float* Wb, int bstep, int halfoff, int D,
                 float* out, bool fin) {
    dim3 grid(cdiv(N, 128), D / 64);
    for (int r0 = 0; r0 < NREL; r0 += rcmax) {
      int rc = (NREL - r0 < rcmax) ? (NREL - r0) : rcmax;
      agg_csr_k<<<cdiv((long long)N * rc * 32, 256), 256, 0, stream>>>(srcs, off, xsrc, S, N, r0, rc);
      bool last = fin && (r0 + rc >= NREL);
      int boff = r0 * bstep + halfoff;
      if (last)
        gemm_f32<false, true, true><<<grid, 256, 0, stream>>>(S, Wb, nullptr, out, N, D, rc * 128, rc * 128, bstep, boff);
      else
        gemm_f32<false, true, false><<<grid, 256, 0, stream>>>(S, Wb, nullptr, out, N, D, rc * 128, rc * 128, bstep, boff);
    }
  };

  auto apply_se = [&](float* xk) {   // xk += gap(xk)[batch] (in place)
    hipMemsetAsync(gapb, 0, NG * 128 * 4, stream);
    gap_sum_k<<<cdiv(N, 64), 128, 0, stream>>>(xk, batch, gapb, N, 128, 64);
    se_k<<<cdiv((long long)N * 32, 256), 256, 0, stream>>>(xk, gapb, ginv, batch, N);
  };

  dim3 g128(cdiv(N, 128), 2);
  dim3 g256(cdiv(N, 128), 4);

  // ---- layers 1 & 4 share agg(x) ----
  gemm_f32<false, false, false><<<g128, 256, 0, stream>>>(x, Rs,  Bsb, x1,   N, 128, 128, 128, 128, 0);
  gemm_f32<false, false, false><<<g128, 256, 0, stream>>>(x, Rf1, Bf1, hbuf, N, 128, 128, 128, 128, 0);
  for (int r0 = 0; r0 < NREL; r0 += rcmax) {
    int rc = (NREL - r0 < rcmax) ? (NREL - r0) : rcmax;
    agg_csr_k<<<cdiv((long long)N * rc * 32, 256), 256, 0, stream>>>(srcs, off, x, S, N, r0, rc);
    bool last = (r0 + rc >= NREL);
    if (last) {
      gemm_f32<false, true, true><<<g128, 256, 0, stream>>>(S, Ws,  nullptr, x1,   N, 128, rc * 128, rc * 128, 128, r0 * 128);
      gemm_f32<false, true, true><<<g128, 256, 0, stream>>>(S, Wf1, nullptr, hbuf, N, 128, rc * 128, rc * 128, 128, r0 * 128);
    } else {
      gemm_f32<false, true, false><<<g128, 256, 0, stream>>>(S, Ws,  nullptr, x1,   N, 128, rc * 128, rc * 128, 128, r0 * 128);
      gemm_f32<false, true, false><<<g128, 256, 0, stream>>>(S, Wf1, nullptr, hbuf, N, 128, rc * 128, rc * 128, 128, r0 * 128);
    }
  }

  // ---- layer 2: x2 = L(x1) ----
  gemm_f32<false, false, false><<<g128, 256, 0, stream>>>(x1, Rs + 1 * 128 * 128, Bsb + 128, x2, N, 128, 128, 128, 128, 0);
  msg(x1, Ws + (size_t)1 * 8 * 128 * 128, 128, 0, 128, x2, true);

  // ---- layer 3: x3 = L(x2) ----
  gemm_f32<false, false, false><<<g128, 256, 0, stream>>>(x2, Rs + 2 * 128 * 128, Bsb + 256, x3, N, 128, 128, 128, 128, 0);
  msg(x2, Ws + (size_t)2 * 8 * 128 * 128, 128, 0, 128, x3, true);

  // ---- layer 5: hb2 = L([h | se1]) ----
  apply_se(x1);   // x1 := se1
  gemm_f32<false, false, false><<<g128, 256, 0, stream>>>(hbuf, Rf23,                 Bf23, hb2, N, 128, 128, 128, 128, 0);
  gemm_f32<false, true,  false><<<g128, 256, 0, stream>>>(x1,   Rf23 + 128 * 128, nullptr, hb2, N, 128, 128, 128, 128, 0);
  msg(hbuf, Wf23, 256, 0,   128, hb2, false);
  msg(x1,   Wf23, 256, 128, 128, hb2, true);

  // ---- layer 6: hbuf = L([hb2 | se2]) ----
  apply_se(x2);   // x2 := se2
  const float* W6 = Wf23 + (size_t)8 * 256 * 128;
  gemm_f32<false, false, false><<<g128, 256, 0, stream>>>(hb2, Rf23 + 256 * 128,       Bf23 + 128, hbuf, N, 128, 128, 128, 128, 0);
  gemm_f32<false, true,  false><<<g128, 256, 0, stream>>>(x2,  Rf23 + 256 * 128 + 128 * 128, nullptr, hbuf, N, 128, 128, 128, 128, 0);
  msg(hb2, W6, 256, 0,   128, hbuf, false);
  msg(x2,  W6, 256, 128, 128, hbuf, true);

  // ---- layer 7: qbuf = L([hbuf | se3]), D=256 ----
  apply_se(x3);   // x3 := se3
  gemm_f32<false, false, false><<<g256, 256, 0, stream>>>(hbuf, Rf4,             Bf4, qbuf, N, 256, 128, 128, 128, 0);
  gemm_f32<false, true,  false><<<g256, 256, 0, stream>>>(x3,   Rf4 + 128 * 256, nullptr, qbuf, N, 256, 128, 128, 128, 0);
  msg(hbuf, Wf4, 256, 0,   256, qbuf, false);
  msg(x3,   Wf4, 256, 128, 256, qbuf, true);

  // ---- degenerate MHA (softmax over size-1 axis == 1 => o == v) + encoder ----
  gemm_f32<true, false, false><<<g256, 256, 0, stream>>>(qbuf, attn_in_w + (size_t)512 * 256,
                                                         attn_in_b + 512, t1, N, 256, 256, 256, 128, 0);
  gemm_f32<true, false, false><<<g256, 256, 0, stream>>>(t1, attn_out_w, attn_out_b, t2, N, 256, 256, 256, 128, 0);
  ln_add_k<<<cdiv(N, 4), 256, 0, stream>>>(t2, qbuf, ln_g, ln_b, t1, N);     // a
  gemm_f32<true, false, false><<<g256, 256, 0, stream>>>(t1, enc_fc_w, enc_fc_b, t2, N, 256, 256, 256, 128, 0);
  ln_add_k<<<cdiv(N, 4), 256, 0, stream>>>(t2, t1, ln_g, ln_b, qbuf, N);     // o

  // pooled + classifier head
  hipMemsetAsync(psum, 0, NG * 256 * 4, stream);
  gap_sum_k<<<cdiv(N, 64), 256, 0, stream>>>(qbuf, batch, psum, N, 256, 64);
  head_k<<<64, 64, 0, stream>>>(psum, ginv, out_w, out_b, (float*)d_out);
}

// Round 4
// 1626.470 us; speedup vs baseline: 10.8822x; 2.6770x over previous
//
#include <hip/hip_runtime.h>
#include <cstdint>
#include <cstddef>

#define NREL 8
#define NG 64
#define LN_EPS 1e-5f
#define NEG_SLOPE 0.01f

typedef unsigned short u16;
typedef short bf16x8 __attribute__((ext_vector_type(8)));
typedef float f32x4 __attribute__((ext_vector_type(4)));

static __device__ __forceinline__ float b2f(u16 h) {
  return __uint_as_float(((unsigned)h) << 16);
}
static __device__ __forceinline__ u16 f2b(float f) {
  unsigned u = __float_as_uint(f);
  u += 0x7fffu + ((u >> 16) & 1u);   // RNE
  return (u16)(u >> 16);
}

// ------------------------------------------------------------------
// setup kernels
// ------------------------------------------------------------------
__global__ void count_edges_k(const int* __restrict__ dst, const int* __restrict__ et,
                              int* __restrict__ cnt, int E) {
  int e = blockIdx.x * blockDim.x + threadIdx.x;
  if (e < E) atomicAdd(&cnt[dst[e] * NREL + et[e]], 1);
}

__global__ void graph_inv_k(const int* __restrict__ batch, float* __restrict__ ginv, int N) {
  int g = threadIdx.x;
  if (g >= NG) return;
  int a, b;
  { int l = 0, h = N; while (l < h) { int m = (l + h) >> 1; if (batch[m] < g) l = m + 1; else h = m; } a = l; }
  { int l = 0, h = N; while (l < h) { int m = (l + h) >> 1; if (batch[m] < g + 1) l = m + 1; else h = m; } b = l; }
  ginv[g] = 1.0f / fmaxf((float)(b - a), 1.0f);
}

#define SCAN_B 256
#define SCAN_I 4

__global__ void scan1_k(const int* __restrict__ in, int* __restrict__ out,
                        int* __restrict__ bsum, int n) {
  __shared__ int sh[SCAN_B];
  int b0 = blockIdx.x * (SCAN_B * SCAN_I);
  int t = threadIdx.x;
  int v[SCAN_I]; int s = 0;
#pragma unroll
  for (int i = 0; i < SCAN_I; ++i) {
    int idx = b0 + t * SCAN_I + i;
    v[i] = idx < n ? in[idx] : 0;
    s += v[i];
  }
  sh[t] = s; __syncthreads();
  for (int off = 1; off < SCAN_B; off <<= 1) {
    int x = (t >= off) ? sh[t - off] : 0; __syncthreads();
    sh[t] += x; __syncthreads();
  }
  int excl = sh[t] - s;
  if (t == SCAN_B - 1) bsum[blockIdx.x] = sh[t];
  int run = excl;
#pragma unroll
  for (int i = 0; i < SCAN_I; ++i) {
    int idx = b0 + t * SCAN_I + i;
    if (idx < n) out[idx] = run;
    run += v[i];
  }
}

__global__ void scan2_k(int* __restrict__ bsum, int nb) {
  __shared__ int sh[1024];
  int t = threadIdx.x;
  int v = t < nb ? bsum[t] : 0;
  sh[t] = v; __syncthreads();
  for (int off = 1; off < 1024; off <<= 1) {
    int x = (t >= off) ? sh[t - off] : 0; __syncthreads();
    sh[t] += x; __syncthreads();
  }
  if (t < nb) bsum[t] = sh[t] - v;
}

__global__ void scan3_k(int* __restrict__ out, const int* __restrict__ bsum, int n, int total) {
  int idx = blockIdx.x * blockDim.x + threadIdx.x;
  if (idx < n) out[idx] += bsum[idx / (SCAN_B * SCAN_I)];
  if (idx == 0) out[n] = total;
}

__global__ void scatter_k(const int* __restrict__ src, const int* __restrict__ dst,
                          const int* __restrict__ et, int* __restrict__ cursor,
                          int* __restrict__ srcs, int E) {
  int e = blockIdx.x * blockDim.x + threadIdx.x;
  if (e >= E) return;
  int key = dst[e] * NREL + et[e];
  int p = atomicAdd(&cursor[key], 1);
  srcs[p] = src[e];
}

// ------------------------------------------------------------------
// weight prep: transpose-cast f32 (.., K-rows, D) -> bf16 B^T [D][KT]
// out[d][r*128+c] = in[(r*rstride + c + coff)*D + d]
// grid: (KT/32, D/32), 256 threads
// ------------------------------------------------------------------
__global__ void wtrans_k(const float* __restrict__ in, u16* __restrict__ out,
                         int rstride, int coff, int D, int KT) {
  __shared__ float tl[32][33];
  int c0 = blockIdx.x * 32;
  int d0 = blockIdx.y * 32;
  int t = threadIdx.x;
  int r = c0 >> 7;
  int rowbase = r * rstride + (c0 & 127) + coff;
#pragma unroll
  for (int i = 0; i < 4; ++i) {
    int cl = (t >> 5) + i * 8;
    tl[cl][t & 31] = in[(size_t)(rowbase + cl) * D + d0 + (t & 31)];
  }
  __syncthreads();
#pragma unroll
  for (int i = 0; i < 4; ++i) {
    int dl = (t >> 5) + i * 8;
    out[(size_t)(d0 + dl) * KT + c0 + (t & 31)] = f2b(tl[t & 31][dl]);
  }
}

// plain cast f32 -> bf16 (n multiple of 4)
__global__ void castf_k(const float* __restrict__ in, u16* __restrict__ out, int n) {
  int i = (blockIdx.x * blockDim.x + threadIdx.x) * 4;
  if (i >= n) return;
  float4 v = *(const float4*)(in + i);
  ushort4 o;
  o.x = f2b(v.x); o.y = f2b(v.y); o.z = f2b(v.z); o.w = f2b(v.w);
  *(ushort4*)(out + i) = o;
}

// ------------------------------------------------------------------
// CSR segment aggregation, bf16 in/out:
// S[seg,:] = (1/max(len,1)) * sum_{e in seg} x[srcs[e],:], seg=(node, r-r0)
// 32 lanes per segment, 4 bf16 per lane
// ------------------------------------------------------------------
__global__ void agg_csr_b(const int* __restrict__ srcs, const int* __restrict__ off,
                          const u16* __restrict__ xin, u16* __restrict__ S,
                          int N, int r0, int rc) {
  int gid = blockIdx.x * blockDim.x + threadIdx.x;
  int seg = gid >> 5;
  int lane = gid & 31;
  if (seg >= N * rc) return;
  int node = seg / rc;
  int r = r0 + (seg - node * rc);
  int key = node * NREL + r;
  int a = off[key], b = off[key + 1];
  float inv = 1.0f / fmaxf((float)(b - a), 1.0f);
  float a0 = 0.f, a1 = 0.f, a2 = 0.f, a3 = 0.f;
  for (int e = a; e < b; ++e) {
    uint2 u = *(const uint2*)(xin + (size_t)srcs[e] * 128 + lane * 4);
    a0 += b2f((u16)(u.x & 0xffff)); a1 += b2f((u16)(u.x >> 16));
    a2 += b2f((u16)(u.y & 0xffff)); a3 += b2f((u16)(u.y >> 16));
  }
  ushort4 o;
  o.x = f2b(a0 * inv); o.y = f2b(a1 * inv); o.z = f2b(a2 * inv); o.w = f2b(a3 * inv);
  *(ushort4*)(S + (size_t)seg * 128 + lane * 4) = o;
}

// ------------------------------------------------------------------
// bf16 MFMA GEMM: C[m,n] (+)= sum_k A[m,k]*B^T[n,k]
// A: [M][lda] bf16, B: [N][ldb] bf16 (B^T layout), C: [M][N] bf16
// BM=BN=128, BK=64, 256 threads = 4 waves (2x2 of 64x64)
// ACC=false: +bias[n]; ACC=true: += C_old.  ACT: leaky-relu.
// LDS XOR-swizzle: 16B slot s of row -> s ^ (row&7)
// ------------------------------------------------------------------
template<bool ACC, bool ACT>
__global__ __launch_bounds__(256)
void gemm_bf16(const u16* __restrict__ A, const u16* __restrict__ B,
               const float* __restrict__ bias, u16* __restrict__ C,
               int M, int N, int K, int lda, int ldb) {
  __shared__ u16 As[128 * 64];
  __shared__ u16 Bs[128 * 64];
  int bm = blockIdx.x * 128;
  int bn = blockIdx.y * 128;
  int t = threadIdx.x;
  int lane = t & 63;
  int wid = t >> 6;
  int wm = (wid >> 1) * 64, wn = (wid & 1) * 64;
  int l15 = lane & 15, l4 = lane >> 4;

  f32x4 acc[4][4];
#pragma unroll
  for (int i = 0; i < 4; ++i)
#pragma unroll
    for (int j = 0; j < 4; ++j)
      acc[i][j] = (f32x4){0.f, 0.f, 0.f, 0.f};

  int srow = t >> 1;            // staging row 0..127
  int shalf = (t & 1) * 4;      // slots 0-3 or 4-7
  int arow = bm + srow;
  const u16* ap = A + (size_t)arow * lda + shalf * 8;
  const u16* bp = B + (size_t)(bn + srow) * ldb + shalf * 8;
  int swz = srow & 7;

  for (int k0 = 0; k0 < K; k0 += 64) {
    __syncthreads();
    // stage A (row guard -> zeros)
    if (arow < M) {
#pragma unroll
      for (int i = 0; i < 4; ++i) {
        uint4 v = *(const uint4*)(ap + k0 + i * 8);
        *(uint4*)&As[srow * 64 + (((shalf + i) ^ swz) << 3)] = v;
      }
    } else {
      uint4 z = {0, 0, 0, 0};
#pragma unroll
      for (int i = 0; i < 4; ++i)
        *(uint4*)&As[srow * 64 + (((shalf + i) ^ swz) << 3)] = z;
    }
    // stage B (N multiple of 128: no guard)
#pragma unroll
    for (int i = 0; i < 4; ++i) {
      uint4 v = *(const uint4*)(bp + k0 + i * 8);
      *(uint4*)&Bs[srow * 64 + (((shalf + i) ^ swz) << 3)] = v;
    }
    __syncthreads();

#pragma unroll
    for (int kk = 0; kk < 2; ++kk) {
      bf16x8 aF[4], bF[4];
#pragma unroll
      for (int mi = 0; mi < 4; ++mi) {
        int row = wm + mi * 16 + l15;
        int slot = (kk * 4 + l4) ^ (row & 7);
        aF[mi] = *(const bf16x8*)&As[row * 64 + slot * 8];
      }
#pragma unroll
      for (int ni = 0; ni < 4; ++ni) {
        int row = wn + ni * 16 + l15;
        int slot = (kk * 4 + l4) ^ (row & 7);
        bF[ni] = *(const bf16x8*)&Bs[row * 64 + slot * 8];
      }
#pragma unroll
      for (int mi = 0; mi < 4; ++mi)
#pragma unroll
        for (int ni = 0; ni < 4; ++ni)
          // swapped operands: D^T so that each lane holds 4 consecutive n
          acc[mi][ni] = __builtin_amdgcn_mfma_f32_16x16x32_bf16(
              bF[ni], aF[mi], acc[mi][ni], 0, 0, 0);
    }
  }

  // epilogue: lane holds m = ..+l15 (fixed), n block of 4 = ..+l4*4
#pragma unroll
  for (int mi = 0; mi < 4; ++mi) {
    int m = bm + wm + mi * 16 + l15;
    if (m >= M) continue;
#pragma unroll
    for (int ni = 0; ni < 4; ++ni) {
      int nb = bn + wn + ni * 16 + l4 * 4;
      float v0 = acc[mi][ni][0], v1 = acc[mi][ni][1];
      float v2 = acc[mi][ni][2], v3 = acc[mi][ni][3];
      u16* cp = C + (size_t)m * N + nb;
      if (ACC) {
        ushort4 o = *(const ushort4*)cp;
        v0 += b2f(o.x); v1 += b2f(o.y); v2 += b2f(o.z); v3 += b2f(o.w);
      } else {
        float4 bv = *(const float4*)(bias + nb);
        v0 += bv.x; v1 += bv.y; v2 += bv.z; v3 += bv.w;
      }
      if (ACT) {
        v0 = v0 > 0.f ? v0 : NEG_SLOPE * v0;
        v1 = v1 > 0.f ? v1 : NEG_SLOPE * v1;
        v2 = v2 > 0.f ? v2 : NEG_SLOPE * v2;
        v3 = v3 > 0.f ? v3 : NEG_SLOPE * v3;
      }
      ushort4 o;
      o.x = f2b(v0); o.y = f2b(v1); o.z = f2b(v2); o.w = f2b(v3);
      *(ushort4*)cp = o;
    }
  }
}

// ------------------------------------------------------------------
// per-graph sum (batch sorted), bf16 input, f32 atomic output
// ------------------------------------------------------------------
__global__ void gap_sum_b(const u16* __restrict__ x, const int* __restrict__ batch,
                          float* __restrict__ out, int N, int C, int npb) {
  int d = threadIdx.x;            // blockDim.x == C
  int n0 = blockIdx.x * npb;
  if (n0 >= N) return;
  int n1 = min(n0 + npb, N);
  float acc = 0.f;
  int g = batch[n0];
  for (int n = n0; n < n1; ++n) {
    int gn = batch[n];
    if (gn != g) { atomicAdd(&out[g * C + d], acc); acc = 0.f; g = gn; }
    acc += b2f(x[(size_t)n * C + d]);
  }
  atomicAdd(&out[g * C + d], acc);
}

// x[n,:] += gap[batch[n],:]*ginv[batch[n]]  (bf16 in-place)
__global__ void se_b(u16* __restrict__ x, const float* __restrict__ gap,
                     const float* __restrict__ ginv, const int* __restrict__ batch, int N) {
  int gid = blockIdx.x * blockDim.x + threadIdx.x;
  int n = gid >> 5;
  int c4 = gid & 31;
  if (n >= N) return;
  int g = batch[n];
  float gi = ginv[g];
  uint2 u = *(uint2*)(x + (size_t)n * 128 + c4 * 4);
  float4 s = *(const float4*)(gap + (size_t)g * 128 + c4 * 4);
  float v0 = b2f((u16)(u.x & 0xffff)) + s.x * gi;
  float v1 = b2f((u16)(u.x >> 16)) + s.y * gi;
  float v2 = b2f((u16)(u.y & 0xffff)) + s.z * gi;
  float v3 = b2f((u16)(u.y >> 16)) + s.w * gi;
  ushort4 o;
  o.x = f2b(v0); o.y = f2b(v1); o.z = f2b(v2); o.w = f2b(v3);
  *(ushort4*)(x + (size_t)n * 128 + c4 * 4) = o;
}

// out = LN(a + b)*g + be (rows of 256), bf16 in/out, f32 params
__global__ void ln_add_b(const u16* __restrict__ a, const u16* __restrict__ b,
                         const float* __restrict__ gp, const float* __restrict__ bp,
                         u16* __restrict__ out, int N) {
  int wid = threadIdx.x >> 6, lane = threadIdx.x & 63;
  int n = blockIdx.x * 4 + wid;
  if (n >= N) return;
  uint2 ua = *(const uint2*)(a + (size_t)n * 256 + lane * 4);
  uint2 ub = *(const uint2*)(b + (size_t)n * 256 + lane * 4);
  float x0 = b2f((u16)(ua.x & 0xffff)) + b2f((u16)(ub.x & 0xffff));
  float x1 = b2f((u16)(ua.x >> 16))    + b2f((u16)(ub.x >> 16));
  float x2 = b2f((u16)(ua.y & 0xffff)) + b2f((u16)(ub.y & 0xffff));
  float x3 = b2f((u16)(ua.y >> 16))    + b2f((u16)(ub.y >> 16));
  float s = x0 + x1 + x2 + x3;
#pragma unroll
  for (int o = 32; o > 0; o >>= 1) s += __shfl_xor(s, o);
  float m = s * (1.0f / 256.0f);
  float d0 = x0 - m, d1 = x1 - m, d2 = x2 - m, d3 = x3 - m;
  float ss = d0 * d0 + d1 * d1 + d2 * d2 + d3 * d3;
#pragma unroll
  for (int o = 32; o > 0; o >>= 1) ss += __shfl_xor(ss, o);
  float rinv = rsqrtf(ss * (1.0f / 256.0f) + LN_EPS);
  float4 vg = *(const float4*)(gp + lane * 4);
  float4 vb = *(const float4*)(bp + lane * 4);
  ushort4 o;
  o.x = f2b(d0 * rinv * vg.x + vb.x);
  o.y = f2b(d1 * rinv * vg.y + vb.y);
  o.z = f2b(d2 * rinv * vg.z + vb.z);
  o.w = f2b(d3 * rinv * vg.w + vb.w);
  *(ushort4*)(out + (size_t)n * 256 + lane * 4) = o;
}

// out[g,cls] = (psum[g]*ginv[g]).out_w[cls] + out_b[cls]
__global__ void head_k(const float* __restrict__ psum, const float* __restrict__ ginv,
                       const float* __restrict__ ow, const float* __restrict__ ob,
                       float* __restrict__ out) {
  int gr = blockIdx.x;
  int lane = threadIdx.x;
  float gi = ginv[gr];
  float4 v = *(const float4*)(psum + gr * 256 + lane * 4);
  float p0 = v.x * gi, p1 = v.y * gi, p2 = v.z * gi, p3 = v.w * gi;
  for (int cls = 0; cls < 10; ++cls) {
    float4 w = *(const float4*)(ow + cls * 256 + lane * 4);
    float s = p0 * w.x + p1 * w.y + p2 * w.z + p3 * w.w;
#pragma unroll
    for (int o = 32; o > 0; o >>= 1) s += __shfl_xor(s, o);
    if (lane == 0) out[gr * 10 + cls] = s + ob[cls];
  }
}

// ------------------------------------------------------------------
extern "C" void kernel_launch(void* const* d_in, const int* in_sizes, int n_in,
                              void* d_out, int out_size, void* d_ws, size_t ws_size,
                              hipStream_t stream) {
  const float* x        = (const float*)d_in[0];
  const int*   eidx     = (const int*)d_in[1];
  const int*   eattr    = (const int*)d_in[2];
  const int*   batch    = (const int*)d_in[3];
  const float* Ws       = (const float*)d_in[4];
  const float* Rs       = (const float*)d_in[5];
  const float* Bsb      = (const float*)d_in[6];
  const float* Wf1      = (const float*)d_in[7];
  const float* Rf1      = (const float*)d_in[8];
  const float* Bf1      = (const float*)d_in[9];
  const float* Wf23     = (const float*)d_in[10];
  const float* Rf23     = (const float*)d_in[11];
  const float* Bf23     = (const float*)d_in[12];
  const float* Wf4      = (const float*)d_in[13];
  const float* Rf4      = (const float*)d_in[14];
  const float* Bf4      = (const float*)d_in[15];
  const float* attn_in_w  = (const float*)d_in[16];
  const float* attn_in_b  = (const float*)d_in[17];
  const float* attn_out_w = (const float*)d_in[18];
  const float* attn_out_b = (const float*)d_in[19];
  const float* enc_fc_w   = (const float*)d_in[20];
  const float* enc_fc_b   = (const float*)d_in[21];
  const float* ln_g       = (const float*)d_in[22];
  const float* ln_bb      = (const float*)d_in[23];
  const float* out_w      = (const float*)d_in[24];
  const float* out_b      = (const float*)d_in[25];

  const int N = in_sizes[0] / 128;
  const int E = in_sizes[1] / 2;
  const int NK = N * NREL;
  const int* src = eidx;
  const int* dst = eidx + E;
  const size_t NB = (size_t)N * 128 * 2;   // one N x 128 bf16 region (256B-mult)

  // ---- workspace layout ----
  char* p = (char*)d_ws;
  auto alloc = [&](size_t bytes) {
    char* r = p;
    p += (bytes + 255) & ~(size_t)255;
    return r;
  };
  float* ginv = (float*)alloc(NG * 4);
  float* psum = (float*)alloc(NG * 256 * 4);
  float* gapb = (float*)alloc(NG * 128 * 4);
  u16* R0 = (u16*)alloc(NB);   // x1   | qbuf lo
  u16* R1 = (u16*)alloc(NB);   // x2   | qbuf hi
  u16* R2 = (u16*)alloc(NB);   // x3   | t1 lo
  u16* R3 = (u16*)alloc(NB);   // hbuf | t1 hi
  u16* R4 = (u16*)alloc(NB);   // hb2  | t2 lo
  u16* xb = (u16*)alloc(NB);   //      | t2 hi
  int* cnt    = (int*)alloc((size_t)NK * 4);
  int* off    = (int*)alloc((size_t)(NK + 1) * 4);
  int* cursor = (int*)alloc((size_t)NK * 4);
  int* srcs   = (int*)alloc((size_t)E * 4);
  int* bsum   = (int*)alloc(2048 * 4);
  // bf16 B^T weight pool
  u16* wm1  = (u16*)alloc((size_t)128 * 1024 * 2);
  u16* wm2  = (u16*)alloc((size_t)128 * 1024 * 2);
  u16* wm3  = (u16*)alloc((size_t)128 * 1024 * 2);
  u16* wm4  = (u16*)alloc((size_t)128 * 1024 * 2);
  u16* wm5h = (u16*)alloc((size_t)128 * 1024 * 2);
  u16* wm5s = (u16*)alloc((size_t)128 * 1024 * 2);
  u16* wm6h = (u16*)alloc((size_t)128 * 1024 * 2);
  u16* wm6s = (u16*)alloc((size_t)128 * 1024 * 2);
  u16* wm7h = (u16*)alloc((size_t)256 * 1024 * 2);
  u16* wm7s = (u16*)alloc((size_t)256 * 1024 * 2);
  u16* wr1  = (u16*)alloc((size_t)128 * 128 * 2);
  u16* wr2  = (u16*)alloc((size_t)128 * 128 * 2);
  u16* wr3  = (u16*)alloc((size_t)128 * 128 * 2);
  u16* wr4  = (u16*)alloc((size_t)128 * 128 * 2);
  u16* wr5h = (u16*)alloc((size_t)128 * 128 * 2);
  u16* wr5s = (u16*)alloc((size_t)128 * 128 * 2);
  u16* wr6h = (u16*)alloc((size_t)128 * 128 * 2);
  u16* wr6s = (u16*)alloc((size_t)128 * 128 * 2);
  u16* wr7h = (u16*)alloc((size_t)256 * 128 * 2);
  u16* wr7s = (u16*)alloc((size_t)256 * 128 * 2);
  u16* wv   = (u16*)alloc((size_t)256 * 256 * 2);
  u16* wo   = (u16*)alloc((size_t)256 * 256 * 2);
  u16* wf   = (u16*)alloc((size_t)256 * 256 * 2);
  size_t used = (size_t)(p - (char*)d_ws);
  u16* S = (u16*)p;
  size_t s_bytes = ws_size > used ? ws_size - used : 0;

  u16* x1 = R0, *x2 = R1, *x3 = R2, *hbuf = R3, *hb2 = R4;
  u16* qbuf = R0;   // N x 256 (R0+R1)
  u16* t1   = R2;   // N x 256 (R2+R3)
  u16* t2   = R4;   // N x 256 (R4+xb)

  int rcmax = (int)(s_bytes / NB);
  if (rcmax > NREL) rcmax = NREL;
  if (rcmax < 1) rcmax = 1;

  auto cdiv = [](long long a, long long b) { return (int)((a + b - 1) / b); };
  int gm = cdiv(N, 128);   // GEMM row blocks

  // ---- CSR build ----
  hipMemsetAsync(cnt, 0, (size_t)NK * 4, stream);
  count_edges_k<<<cdiv(E, 256), 256, 0, stream>>>(dst, eattr, cnt, E);
  int nb = cdiv(NK, SCAN_B * SCAN_I);
  scan1_k<<<nb, SCAN_B, 0, stream>>>(cnt, off, bsum, NK);
  scan2_k<<<1, 1024, 0, stream>>>(bsum, nb);
  scan3_k<<<cdiv(NK, 256), 256, 0, stream>>>(off, bsum, NK, E);
  hipMemcpyAsync(cursor, off, (size_t)NK * 4, hipMemcpyDeviceToDevice, stream);
  scatter_k<<<cdiv(E, 256), 256, 0, stream>>>(src, dst, eattr, cursor, srcs, E);
  graph_inv_k<<<1, 64, 0, stream>>>(batch, ginv, N);

  // ---- weight prep ----
  castf_k<<<cdiv((long long)N * 128, 1024), 256, 0, stream>>>(x, xb, N * 128);
  dim3 w128(32, 4), w128d256(32, 8), wroot(4, 4), wrootd256(4, 8);
  wtrans_k<<<w128, 256, 0, stream>>>(Ws,                        wm1, 128, 0, 128, 1024);
  wtrans_k<<<w128, 256, 0, stream>>>(Ws + (size_t)8 * 128 * 128, wm2, 128, 0, 128, 1024);
  wtrans_k<<<w128, 256, 0, stream>>>(Ws + (size_t)16 * 128 * 128, wm3, 128, 0, 128, 1024);
  wtrans_k<<<w128, 256, 0, stream>>>(Wf1,                       wm4, 128, 0, 128, 1024);
  wtrans_k<<<w128, 256, 0, stream>>>(Wf23,                      wm5h, 256, 0,   128, 1024);
  wtrans_k<<<w128, 256, 0, stream>>>(Wf23,                      wm5s, 256, 128, 128, 1024);
  const float* W6 = Wf23 + (size_t)8 * 256 * 128;
  wtrans_k<<<w128, 256, 0, stream>>>(W6,                        wm6h, 256, 0,   128, 1024);
  wtrans_k<<<w128, 256, 0, stream>>>(W6,                        wm6s, 256, 128, 128, 1024);
  wtrans_k<<<w128d256, 256, 0, stream>>>(Wf4,                   wm7h, 256, 0,   256, 1024);
  wtrans_k<<<w128d256, 256, 0, stream>>>(Wf4,                   wm7s, 256, 128, 256, 1024);
  wtrans_k<<<wroot, 256, 0, stream>>>(Rs,                       wr1, 128, 0, 128, 128);
  wtrans_k<<<wroot, 256, 0, stream>>>(Rs + 128 * 128,           wr2, 128, 0, 128, 128);
  wtrans_k<<<wroot, 256, 0, stream>>>(Rs + 2 * 128 * 128,       wr3, 128, 0, 128, 128);
  wtrans_k<<<wroot, 256, 0, stream>>>(Rf1,                      wr4, 128, 0, 128, 128);
  wtrans_k<<<wroot, 256, 0, stream>>>(Rf23,                     wr5h, 256, 0,   128, 128);
  wtrans_k<<<wroot, 256, 0, stream>>>(Rf23,                     wr5s, 256, 128, 128, 128);
  wtrans_k<<<wroot, 256, 0, stream>>>(Rf23 + 256 * 128,         wr6h, 256, 0,   128, 128);
  wtrans_k<<<wroot, 256, 0, stream>>>(Rf23 + 256 * 128,         wr6s, 256, 128, 128, 128);
  wtrans_k<<<wrootd256, 256, 0, stream>>>(Rf4,                  wr7h, 256, 0,   256, 128);
  wtrans_k<<<wrootd256, 256, 0, stream>>>(Rf4,                  wr7s, 256, 128, 256, 128);
  castf_k<<<cdiv(256 * 256, 1024), 256, 0, stream>>>(attn_in_w + (size_t)512 * 256, wv, 256 * 256);
  castf_k<<<cdiv(256 * 256, 1024), 256, 0, stream>>>(attn_out_w, wo, 256 * 256);
  castf_k<<<cdiv(256 * 256, 1024), 256, 0, stream>>>(enc_fc_w,   wf, 256 * 256);

  dim3 g1(gm, 1), g2(gm, 2);

  // msg pass: out += sum_r agg_r(xsrc) @ W_r  (bf16 B^T pool, K chunked by rcmax)
  auto msg = [&](const u16* xsrc, const u16* Wbt, int D, u16* out, bool fin) {
    dim3 grid(gm, D / 128);
    for (int r0 = 0; r0 < NREL; r0 += rcmax) {
      int rc = (NREL - r0 < rcmax) ? (NREL - r0) : rcmax;
      agg_csr_b<<<cdiv((long long)N * rc * 32, 256), 256, 0, stream>>>(srcs, off, xsrc, S, N, r0, rc);
      bool last = fin && (r0 + rc >= NREL);
      const u16* Bp = Wbt + r0 * 128;
      if (last)
        gemm_bf16<true, true><<<grid, 256, 0, stream>>>(S, Bp, nullptr, out, N, D, rc * 128, rc * 128, 1024);
      else
        gemm_bf16<true, false><<<grid, 256, 0, stream>>>(S, Bp, nullptr, out, N, D, rc * 128, rc * 128, 1024);
    }
  };

  auto apply_se = [&](u16* xk) {
    hipMemsetAsync(gapb, 0, NG * 128 * 4, stream);
    gap_sum_b<<<cdiv(N, 64), 128, 0, stream>>>(xk, batch, gapb, N, 128, 64);
    se_b<<<cdiv((long long)N * 32, 256), 256, 0, stream>>>(xk, gapb, ginv, batch, N);
  };

  // ---- layers 1 & 4 (share agg(x)) ----
  gemm_bf16<false, false><<<g1, 256, 0, stream>>>(xb, wr1, Bsb, x1,   N, 128, 128, 128, 128);
  gemm_bf16<false, false><<<g1, 256, 0, stream>>>(xb, wr4, Bf1, hbuf, N, 128, 128, 128, 128);
  for (int r0 = 0; r0 < NREL; r0 += rcmax) {
    int rc = (NREL - r0 < rcmax) ? (NREL - r0) : rcmax;
    agg_csr_b<<<cdiv((long long)N * rc * 32, 256), 256, 0, stream>>>(srcs, off, xb, S, N, r0, rc);
    bool last = (r0 + rc >= NREL);
    if (last) {
      gemm_bf16<true, true><<<g1, 256, 0, stream>>>(S, wm1 + r0 * 128, nullptr, x1,   N, 128, rc * 128, rc * 128, 1024);
      gemm_bf16<true, true><<<g1, 256, 0, stream>>>(S, wm4 + r0 * 128, nullptr, hbuf, N, 128, rc * 128, rc * 128, 1024);
    } else {
      gemm_bf16<true, false><<<g1, 256, 0, stream>>>(S, wm1 + r0 * 128, nullptr, x1,   N, 128, rc * 128, rc * 128, 1024);
      gemm_bf16<true, false><<<g1, 256, 0, stream>>>(S, wm4 + r0 * 128, nullptr, hbuf, N, 128, rc * 128, rc * 128, 1024);
    }
  }

  // ---- layer 2 ----
  gemm_bf16<false, false><<<g1, 256, 0, stream>>>(x1, wr2, Bsb + 128, x2, N, 128, 128, 128, 128);
  msg(x1, wm2, 128, x2, true);
  // ---- layer 3 ----
  gemm_bf16<false, false><<<g1, 256, 0, stream>>>(x2, wr3, Bsb + 256, x3, N, 128, 128, 128, 128);
  msg(x2, wm3, 128, x3, true);

  // ---- layer 5: hb2 = L([hbuf | se1]) ----
  apply_se(x1);
  gemm_bf16<false, false><<<g1, 256, 0, stream>>>(hbuf, wr5h, Bf23, hb2, N, 128, 128, 128, 128);
  gemm_bf16<true,  false><<<g1, 256, 0, stream>>>(x1,   wr5s, nullptr, hb2, N, 128, 128, 128, 128);
  msg(hbuf, wm5h, 128, hb2, false);
  msg(x1,   wm5s, 128, hb2, true);

  // ---- layer 6: hbuf = L([hb2 | se2]) ----
  apply_se(x2);
  gemm_bf16<false, false><<<g1, 256, 0, stream>>>(hb2, wr6h, Bf23 + 128, hbuf, N, 128, 128, 128, 128);
  gemm_bf16<true,  false><<<g1, 256, 0, stream>>>(x2,  wr6s, nullptr, hbuf, N, 128, 128, 128, 128);
  msg(hb2, wm6h, 128, hbuf, false);
  msg(x2,  wm6s, 128, hbuf, true);

  // ---- layer 7: qbuf = L([hbuf | se3]), D=256 ----
  apply_se(x3);
  gemm_bf16<false, false><<<g2, 256, 0, stream>>>(hbuf, wr7h, Bf4, qbuf, N, 256, 128, 128, 128);
  gemm_bf16<true,  false><<<g2, 256, 0, stream>>>(x3,   wr7s, nullptr, qbuf, N, 256, 128, 128, 128);
  msg(hbuf, wm7h, 256, qbuf, false);
  msg(x3,   wm7s, 256, qbuf, true);

  // ---- degenerate MHA (o == v) + encoder ----
  gemm_bf16<false, false><<<g2, 256, 0, stream>>>(qbuf, wv, attn_in_b + 512, t1, N, 256, 256, 256, 256);
  gemm_bf16<false, false><<<g2, 256, 0, stream>>>(t1,   wo, attn_out_b,      t2, N, 256, 256, 256, 256);
  ln_add_b<<<cdiv(N, 4), 256, 0, stream>>>(t2, qbuf, ln_g, ln_bb, t1, N);
  gemm_bf16<false, false><<<g2, 256, 0, stream>>>(t1,   wf, enc_fc_b,        t2, N, 256, 256, 256, 256);
  ln_add_b<<<cdiv(N, 4), 256, 0, stream>>>(t2, t1, ln_g, ln_bb, qbuf, N);

  // ---- pooled + head ----
  hipMemsetAsync(psum, 0, NG * 256 * 4, stream);
  gap_sum_b<<<cdiv(N, 64), 256, 0, stream>>>(qbuf, batch, psum, N, 256, 64);
  head_k<<<64, 64, 0, stream>>>(psum, ginv, out_w, out_b, (float*)d_out);
}